// Round 5
// baseline (396.357 us; speedup 1.0000x reference)
//
#include <hip/hip_runtime.h>
#include <math.h>

// MultiTaskGNN: 2-layer GAT + BN + ELU + two heads. N=50000, E=400000.
// R5: atomic denominators in ew pass (no wave_sums in agg), BN folded to S/T,
// fast ELU (__expf), 4/8 edges-in-flight agg loops with padded CSR.

typedef unsigned short ushort_t;
typedef __attribute__((ext_vector_type(8))) unsigned short ushort8;
typedef __attribute__((ext_vector_type(4))) unsigned short ushort4v;
typedef __attribute__((ext_vector_type(8))) short short8;
typedef __attribute__((ext_vector_type(4))) float f32x4;

#define EPS_BN 1e-5f

__device__ __forceinline__ ushort_t f2bf(float f) {  // RNE
  unsigned u = __float_as_uint(f);
  unsigned r = u + 0x7fffu + ((u >> 16) & 1u);
  return (ushort_t)(r >> 16);
}
__device__ __forceinline__ float bf2f(ushort_t h) {
  return __uint_as_float((unsigned)h << 16);
}
__device__ __forceinline__ float leaky02(float x) { return x >= 0.f ? x : 0.2f * x; }
__device__ __forceinline__ float elu_fast(float x) {
  return x > 0.f ? x : __expf(x) - 1.f;
}

__device__ __forceinline__ int wave_incl_scan(int v, int lane) {
#pragma unroll
  for (int off = 1; off < 64; off <<= 1) {
    int t = __shfl_up(v, off, 64);
    if (lane >= off) v += t;
  }
  return v;
}

__device__ __forceinline__ void gld_lds16(const ushort_t* g, ushort_t* l) {
  __builtin_amdgcn_global_load_lds(
      (const __attribute__((address_space(1))) unsigned int*)g,
      (__attribute__((address_space(3))) unsigned int*)l, 16, 0, 0);
}

// ---------------- prep: zero counters/dens, W transposes, BN fold, csr pad ----------------
__global__ void prep_kernel(int* __restrict__ counts, int* __restrict__ cursor,
                            float* __restrict__ den1, float* __restrict__ den2,
                            int* __restrict__ csr_src,
                            const float* __restrict__ W1, const float* __restrict__ W2,
                            ushort_t* __restrict__ W1t, ushort_t* __restrict__ W2t,
                            const float* __restrict__ b1, const float* __restrict__ bn1w,
                            const float* __restrict__ bn1b, const float* __restrict__ bn1m,
                            const float* __restrict__ bn1v,
                            const float* __restrict__ b2, const float* __restrict__ bn2w,
                            const float* __restrict__ bn2b, const float* __restrict__ bn2m,
                            const float* __restrict__ bn2v,
                            float* __restrict__ S1, float* __restrict__ T1,
                            float* __restrict__ S2, float* __restrict__ T2, int N, int E) {
  int i = blockIdx.x * 256 + threadIdx.x;
  if (i < N) {
    counts[i] = 0;
    cursor[i] = 0;
    den2[i] = 0.f;
    float4 z = make_float4(0.f, 0.f, 0.f, 0.f);
    *(float4*)&den1[i * 4] = z;
    return;
  }
  int j = i - N;
  if (j < 256 * 256) {
    int k = j >> 8, n2 = j & 255;
    W1t[n2 * 256 + k] = f2bf(W1[j]);
    return;
  }
  j -= 256 * 256;
  if (j < 256 * 64) {
    int k = j >> 6, n2 = j & 63;
    W2t[n2 * 256 + k] = f2bf(W2[j]);
    return;
  }
  j -= 256 * 64;
  if (j < 256) {
    float s = bn1w[j] * rsqrtf(bn1v[j] + EPS_BN);
    S1[j] = s;
    T1[j] = (b1[j] - bn1m[j]) * s + bn1b[j];
    return;
  }
  j -= 256;
  if (j < 64) {
    float s = bn2w[j] * rsqrtf(bn2v[j] + EPS_BN);
    S2[j] = s;
    T2[j] = (b2[j] - bn2m[j]) * s + bn2b[j];
    return;
  }
  j -= 64;
  if (j < 64) csr_src[E + j] = 0;  // pad so unclamped tail loads hit a valid index
}

// ---------------- graph build ----------------
__global__ void hist_kernel(const int* __restrict__ dst, int* __restrict__ counts, int E) {
  int e = blockIdx.x * blockDim.x + threadIdx.x;
  if (e < E) atomicAdd(&counts[dst[e]], 1);
}

__global__ __launch_bounds__(256) void scan_chunks_kernel(const int* __restrict__ counts,
                                                          int* __restrict__ offsets,
                                                          int* __restrict__ partials, int N) {
  __shared__ int ws[4];
  int tid = threadIdx.x, lane = tid & 63, wv = tid >> 6;
  int i = blockIdx.x * 256 + tid;
  int v = (i < N) ? counts[i] : 0;
  int incl = wave_incl_scan(v, lane);
  if (lane == 63) ws[wv] = incl;
  __syncthreads();
  int wbase = 0;
  for (int k = 0; k < wv; ++k) wbase += ws[k];
  if (i < N) offsets[i] = wbase + incl - v;
  if (tid == 255) partials[blockIdx.x] = wbase + incl;
}

__global__ __launch_bounds__(256) void scan_partials_kernel(const int* __restrict__ partials,
                                                            int* __restrict__ pprefix, int nb) {
  __shared__ int ws[4];
  int tid = threadIdx.x, lane = tid & 63, wv = tid >> 6;
  int v = (tid < nb) ? partials[tid] : 0;
  int incl = wave_incl_scan(v, lane);
  if (lane == 63) ws[wv] = incl;
  __syncthreads();
  int wbase = 0;
  for (int k = 0; k < wv; ++k) wbase += ws[k];
  if (tid < nb) pprefix[tid] = wbase + incl - v;
  if (tid == 255) pprefix[nb] = wbase + incl;
}

__global__ void add_base_kernel(int* __restrict__ offsets, const int* __restrict__ pprefix,
                                int N, int nb) {
  int i = blockIdx.x * 256 + threadIdx.x;
  if (i < N) offsets[i] += pprefix[blockIdx.x];
  if (i == 0) offsets[N] = pprefix[nb];
}

__global__ void scatter_kernel(const int* __restrict__ src, const int* __restrict__ dst,
                               const int* __restrict__ offsets, int* __restrict__ cursor,
                               int* __restrict__ csr_src, int* __restrict__ csr_dst, int E) {
  int e = blockIdx.x * blockDim.x + threadIdx.x;
  if (e < E) {
    int d = dst[e];
    int p = atomicAdd(&cursor[d], 1);
    int pos = offsets[d] + p;
    csr_src[pos] = src[e];
    csr_dst[pos] = d;
  }
}

// ---------------- edge weights + atomic denominators (layer 1) ----------------
__global__ void edge_weights1(const int* __restrict__ csr_src, const int* __restrict__ csr_dst,
                              const float* __restrict__ as1, const float* __restrict__ ad1,
                              float* __restrict__ we, float* __restrict__ wself,
                              float* __restrict__ den1, int E, int N) {
  int t = blockIdx.x * 256 + threadIdx.x;
  if (t < E) {
    int s = csr_src[t], d = csr_dst[t];
    float4 a = *(const float4*)&as1[s * 4];
    float4 b = *(const float4*)&ad1[d * 4];
    float4 o;
    o.x = __expf(leaky02(a.x + b.x));
    o.y = __expf(leaky02(a.y + b.y));
    o.z = __expf(leaky02(a.z + b.z));
    o.w = __expf(leaky02(a.w + b.w));
    *(float4*)&we[(size_t)t * 4] = o;
    atomicAdd(&den1[d * 4 + 0], o.x);
    atomicAdd(&den1[d * 4 + 1], o.y);
    atomicAdd(&den1[d * 4 + 2], o.z);
    atomicAdd(&den1[d * 4 + 3], o.w);
  } else if (t < E + N) {
    int n = t - E;
    float4 a = *(const float4*)&as1[n * 4];
    float4 b = *(const float4*)&ad1[n * 4];
    float4 o;
    o.x = __expf(leaky02(a.x + b.x));
    o.y = __expf(leaky02(a.y + b.y));
    o.z = __expf(leaky02(a.z + b.z));
    o.w = __expf(leaky02(a.w + b.w));
    *(float4*)&wself[n * 4] = o;
  }
}

// ---------------- edge weights + atomic denominator (layer 2) ----------------
__global__ void edge_weights2(const int* __restrict__ csr_src, const int* __restrict__ csr_dst,
                              const float* __restrict__ as2, const float* __restrict__ ad2,
                              float* __restrict__ we, float* __restrict__ wself,
                              float* __restrict__ den2, int E, int N) {
  int t = blockIdx.x * 256 + threadIdx.x;
  if (t < E) {
    int d = csr_dst[t];
    float o = __expf(leaky02(as2[csr_src[t]] + ad2[d]));
    we[t] = o;
    atomicAdd(&den2[d], o);
  } else if (t < E + N) {
    int n = t - E;
    wself[n] = __expf(leaky02(as2[n] + ad2[n]));
  }
}

// ---------------- MFMA bf16 GEMM + fused alpha epilogue ----------------
template <int WM, bool CASTA>
__global__ __launch_bounds__(WM * 64) void mfma_gemm_fused(
    const void* __restrict__ Ain, const ushort_t* __restrict__ Bt,
    ushort_t* __restrict__ C, const float* __restrict__ avs, const float* __restrict__ avd,
    float* __restrict__ as_out, float* __restrict__ ad_out, int M, int Nt, int K, int H) {
  constexpr int BM = WM * 32;
  constexpr int NB = 4 / WM;
  __shared__ ushort_t As[BM * 32];
  __shared__ ushort_t Bs[64 * 32];
  const int t = threadIdx.x;
  const int w = t >> 6, l = t & 63;
  const int m0 = blockIdx.y * BM;
  const int n0 = blockIdx.x * 64;
  const int head = n0 >> 6;

  f32x4 zero4 = {0.f, 0.f, 0.f, 0.f};
  f32x4 acc[2][4];
#pragma unroll
  for (int i = 0; i < 2; ++i)
#pragma unroll
    for (int j = 0; j < 4; ++j) acc[i][j] = zero4;

  const int scol = (l & 3) * 8;
  const ushort_t* Bgb[NB];
  ushort_t* Bsl[NB];
#pragma unroll
  for (int b = 0; b < NB; ++b) {
    int r = (b * WM + w) * 16 + (l >> 2);
    Bgb[b] = Bt + (size_t)(n0 + r) * K + scol;
    Bsl[b] = &Bs[(b * WM + w) * 512];
  }
  const ushort_t* Aga[2];
  ushort_t* Asl[2];
  const float* Axg = nullptr;
  ushort_t* AsWc = nullptr;
  if (CASTA) {
    int ar = t >> 1, ac = (t & 1) * 16;
    Axg = (const float*)Ain + (size_t)min(m0 + ar, M - 1) * K + ac;
    AsWc = &As[ar * 32 + ac];
  } else {
#pragma unroll
    for (int a = 0; a < 2; ++a) {
      int r = (a * WM + w) * 16 + (l >> 2);
      int gr = min(m0 + r, M - 1);
      Aga[a] = (const ushort_t*)Ain + (size_t)gr * K + scol;
      Asl[a] = &As[(a * WM + w) * 512];
    }
  }

  for (int k0 = 0; k0 < K; k0 += 32) {
    if (CASTA) {
      float4 f0 = *(const float4*)(Axg + k0);
      float4 f1 = *(const float4*)(Axg + k0 + 4);
      float4 f2 = *(const float4*)(Axg + k0 + 8);
      float4 f3 = *(const float4*)(Axg + k0 + 12);
      __syncthreads();
#pragma unroll
      for (int b = 0; b < NB; ++b) gld_lds16(Bgb[b] + k0, Bsl[b]);
      ushort8 u0, u1;
      u0[0] = f2bf(f0.x); u0[1] = f2bf(f0.y); u0[2] = f2bf(f0.z); u0[3] = f2bf(f0.w);
      u0[4] = f2bf(f1.x); u0[5] = f2bf(f1.y); u0[6] = f2bf(f1.z); u0[7] = f2bf(f1.w);
      u1[0] = f2bf(f2.x); u1[1] = f2bf(f2.y); u1[2] = f2bf(f2.z); u1[3] = f2bf(f2.w);
      u1[4] = f2bf(f3.x); u1[5] = f2bf(f3.y); u1[6] = f2bf(f3.z); u1[7] = f2bf(f3.w);
      *(ushort8*)AsWc = u0;
      *(ushort8*)(AsWc + 8) = u1;
      __syncthreads();
    } else {
      __syncthreads();
#pragma unroll
      for (int a = 0; a < 2; ++a) gld_lds16(Aga[a] + k0, Asl[a]);
#pragma unroll
      for (int b = 0; b < NB; ++b) gld_lds16(Bgb[b] + k0, Bsl[b]);
      __syncthreads();
    }
    const int kq = (l >> 4) * 8;
    short8 af[2], bfr[4];
#pragma unroll
    for (int i = 0; i < 2; ++i)
      af[i] = *(const short8*)&As[(w * 32 + i * 16 + (l & 15)) * 32 + kq];
#pragma unroll
    for (int j = 0; j < 4; ++j)
      bfr[j] = *(const short8*)&Bs[(j * 16 + (l & 15)) * 32 + kq];
#pragma unroll
    for (int i = 0; i < 2; ++i)
#pragma unroll
      for (int j = 0; j < 4; ++j)
        acc[i][j] = __builtin_amdgcn_mfma_f32_16x16x32_bf16(af[i], bfr[j], acc[i][j], 0, 0, 0);
  }

  const int rbase = m0 + w * 32 + (l >> 4) * 4;
  const int cbase = n0 + (l & 15);
#pragma unroll
  for (int i = 0; i < 2; ++i)
#pragma unroll
    for (int j = 0; j < 4; ++j)
#pragma unroll
      for (int r = 0; r < 4; ++r) {
        int row = rbase + i * 16 + r;
        if (row < M) C[(size_t)row * Nt + cbase + j * 16] = f2bf(acc[i][j][r]);
      }

  float asw[4], adw[4];
#pragma unroll
  for (int j = 0; j < 4; ++j) {
    asw[j] = avs[head * 64 + (l & 15) + j * 16];
    adw[j] = avd[head * 64 + (l & 15) + j * 16];
  }
#pragma unroll
  for (int i = 0; i < 2; ++i)
#pragma unroll
    for (int r = 0; r < 4; ++r) {
      float s_ = acc[i][0][r] * asw[0] + acc[i][1][r] * asw[1] +
                 acc[i][2][r] * asw[2] + acc[i][3][r] * asw[3];
      float d_ = acc[i][0][r] * adw[0] + acc[i][1][r] * adw[1] +
                 acc[i][2][r] * adw[2] + acc[i][3][r] * adw[3];
#pragma unroll
      for (int o = 1; o < 16; o <<= 1) {
        s_ += __shfl_xor(s_, o, 64);
        d_ += __shfl_xor(d_, o, 64);
      }
      if ((l & 15) == 0) {
        int row = rbase + i * 16 + r;
        if (row < M) {
          as_out[(size_t)row * H + head] = s_;
          ad_out[(size_t)row * H + head] = d_;
        }
      }
    }
}

// ---------------- layer 1 agg: 4 edges/iter, precomputed den, folded BN ----------------
__global__ __launch_bounds__(256) void agg1_kernel(
    const ushort_t* __restrict__ h1, const int* __restrict__ offsets,
    const int* __restrict__ csr, const float* __restrict__ we,
    const float* __restrict__ wself, const float* __restrict__ den1,
    const float* __restrict__ S1, const float* __restrict__ T1,
    ushort_t* __restrict__ out, int N) {
  int n = blockIdx.x * 4 + (threadIdx.x >> 6);
  int l = threadIdx.x & 63;
  if (n >= N) return;
  const int g = l >> 5, ll = l & 31, hh = ll >> 3;
  int off = offsets[n], deg = offsets[n + 1] - off;
  float acc[8] = {0, 0, 0, 0, 0, 0, 0, 0};
  const int* csrp = csr + off;
  const float* wep = we + (size_t)off * 4 + hh;
  const size_t hoff = (size_t)ll * 8;

  for (int j = 0; j < deg; j += 4) {
    int ea = j + g, eb = j + g + 2;
    int sa = csrp[ea];              // padded csr: always a valid index
    int sb = csrp[eb];
    float wa = wep[(size_t)ea * 4];
    float wb = wep[(size_t)eb * 4];
    if (ea >= deg) wa = 0.f;
    if (eb >= deg) wb = 0.f;
    ushort8 ha = *(const ushort8*)&h1[(size_t)sa * 256 + hoff];
    ushort8 hb = *(const ushort8*)&h1[(size_t)sb * 256 + hoff];
#pragma unroll
    for (int k = 0; k < 8; ++k) acc[k] = fmaf(wa, bf2f(ha[k]), acc[k]);
#pragma unroll
    for (int k = 0; k < 8; ++k) acc[k] = fmaf(wb, bf2f(hb[k]), acc[k]);
  }
#pragma unroll
  for (int k = 0; k < 8; ++k) acc[k] += __shfl_xor(acc[k], 32, 64);

  // self loop + denominator
  float wsh = wself[n * 4 + hh];
  ushort8 hn = *(const ushort8*)&h1[(size_t)n * 256 + hoff];
#pragma unroll
  for (int k = 0; k < 8; ++k) acc[k] = fmaf(wsh, bf2f(hn[k]), acc[k]);
  float den = den1[n * 4 + hh] + wsh;
  float inv = 1.f / (den + 1e-16f);

  int c0 = ll * 8 + g * 4;
  float4 Sv = *(const float4*)&S1[c0];
  float4 Tv = *(const float4*)&T1[c0];
  float Sf[4] = {Sv.x, Sv.y, Sv.z, Sv.w};
  float Tf[4] = {Tv.x, Tv.y, Tv.z, Tv.w};
  ushort4v o4;
#pragma unroll
  for (int q = 0; q < 4; ++q) {
    float o = fmaf(acc[g * 4 + q], inv * Sf[q], Tf[q]);
    o4[q] = f2bf(elu_fast(o));
  }
  *(ushort4v*)&out[(size_t)n * 256 + c0] = o4;
}

// ---------------- layer 2 agg: 8 edges/iter, fused heads ----------------
__global__ __launch_bounds__(256) void agg2_kernel(
    const ushort_t* __restrict__ h2, const int* __restrict__ offsets,
    const int* __restrict__ csr, const float* __restrict__ we,
    const float* __restrict__ wself, const float* __restrict__ den2,
    const float* __restrict__ S2, const float* __restrict__ T2,
    const float* __restrict__ Wr, const float* __restrict__ br,
    const float* __restrict__ Wc, const float* __restrict__ bc,
    float* __restrict__ out_reg, float* __restrict__ out_clf, int N) {
  int n = blockIdx.x * 4 + (threadIdx.x >> 6);
  int l = threadIdx.x & 63;
  if (n >= N) return;
  const int g = l >> 4, ll = l & 15;
  int off = offsets[n], deg = offsets[n + 1] - off;
  float acc[4] = {0, 0, 0, 0};
  const int* csrp = csr + off;
  const float* wep = we + off;
  const size_t hoff = (size_t)ll * 4;

  for (int j = 0; j < deg; j += 8) {
    int ea = j + g, eb = j + g + 4;
    int sa = csrp[ea];
    int sb = csrp[eb];
    float wa = wep[ea];
    float wb = wep[eb];
    if (ea >= deg) wa = 0.f;
    if (eb >= deg) wb = 0.f;
    ushort4v ha = *(const ushort4v*)&h2[(size_t)sa * 64 + hoff];
    ushort4v hb = *(const ushort4v*)&h2[(size_t)sb * 64 + hoff];
#pragma unroll
    for (int k = 0; k < 4; ++k) acc[k] = fmaf(wa, bf2f(ha[k]), acc[k]);
#pragma unroll
    for (int k = 0; k < 4; ++k) acc[k] = fmaf(wb, bf2f(hb[k]), acc[k]);
  }
#pragma unroll
  for (int k = 0; k < 4; ++k) {
    acc[k] += __shfl_xor(acc[k], 16, 64);
    acc[k] += __shfl_xor(acc[k], 32, 64);
  }
  float ws = wself[n];
  ushort4v hn = *(const ushort4v*)&h2[(size_t)n * 64 + hoff];
#pragma unroll
  for (int k = 0; k < 4; ++k) acc[k] = fmaf(ws, bf2f(hn[k]), acc[k]);
  float den = den2[n] + ws;
  float inv = 1.f / (den + 1e-16f);

  int c0 = ll * 4;
  float4 Sv = *(const float4*)&S2[c0];
  float4 Tv = *(const float4*)&T2[c0];
  float4 wr = *(const float4*)&Wr[c0];
  float4 wc = *(const float4*)&Wc[c0];
  float Sf[4] = {Sv.x, Sv.y, Sv.z, Sv.w};
  float Tf[4] = {Tv.x, Tv.y, Tv.z, Tv.w};
  float wrf[4] = {wr.x, wr.y, wr.z, wr.w};
  float wcf[4] = {wc.x, wc.y, wc.z, wc.w};
  float rs = 0.f, cs = 0.f;
#pragma unroll
  for (int q = 0; q < 4; ++q) {
    float o = fmaf(acc[q], inv * Sf[q], Tf[q]);
    o = elu_fast(o);
    rs = fmaf(o, wrf[q], rs);
    cs = fmaf(o, wcf[q], cs);
  }
  // features duplicated across the 4 groups; reduce within one 16-lane group
#pragma unroll
  for (int o = 1; o < 16; o <<= 1) {
    rs += __shfl_xor(rs, o, 64);
    cs += __shfl_xor(cs, o, 64);
  }
  if (l == 0) {
    out_reg[n] = rs + br[0];
    float z = cs + bc[0];
    out_clf[n] = 1.f / (1.f + __expf(-z));
  }
}

// ---------------- launcher ----------------
extern "C" void kernel_launch(void* const* d_in, const int* in_sizes, int n_in,
                              void* d_out, int out_size, void* d_ws, size_t ws_size,
                              hipStream_t stream) {
  const float* x      = (const float*)d_in[0];
  const int*   ei     = (const int*)d_in[1];
  const float* W1     = (const float*)d_in[2];
  const float* a_src1 = (const float*)d_in[3];
  const float* a_dst1 = (const float*)d_in[4];
  const float* b1     = (const float*)d_in[5];
  const float* bn1w   = (const float*)d_in[6];
  const float* bn1b   = (const float*)d_in[7];
  const float* bn1m   = (const float*)d_in[8];
  const float* bn1v   = (const float*)d_in[9];
  const float* W2     = (const float*)d_in[10];
  const float* a_src2 = (const float*)d_in[11];
  const float* a_dst2 = (const float*)d_in[12];
  const float* b2     = (const float*)d_in[13];
  const float* bn2w   = (const float*)d_in[14];
  const float* bn2b   = (const float*)d_in[15];
  const float* bn2m   = (const float*)d_in[16];
  const float* bn2v   = (const float*)d_in[17];
  const float* Wr     = (const float*)d_in[18];
  const float* br     = (const float*)d_in[19];
  const float* Wc     = (const float*)d_in[20];
  const float* bc     = (const float*)d_in[21];

  const int N = in_sizes[0] / 256;  // 50000
  const int E = in_sizes[1] / 2;    // 400000
  const int* srcv = ei;
  const int* dstv = ei + E;

  char* w = (char*)d_ws;
  auto alloc = [&](size_t bytes) {
    char* p = w;
    w += (bytes + 255) & ~(size_t)255;
    return p;
  };
  const int nb = (N + 255) / 256;
  int* counts    = (int*)alloc((size_t)N * 4);
  int* cursor    = (int*)alloc((size_t)N * 4);
  int* offsets   = (int*)alloc((size_t)(N + 1) * 4);
  int* partials  = (int*)alloc((size_t)nb * 4);
  int* pprefix   = (int*)alloc((size_t)(nb + 1) * 4);
  int* csr_src   = (int*)alloc((size_t)(E + 64) * 4);   // +64 zero pad
  int* csr_dst   = (int*)alloc((size_t)E * 4);
  float* as1     = (float*)alloc((size_t)N * 4 * 4);
  float* ad1     = (float*)alloc((size_t)N * 4 * 4);
  float* as2     = (float*)alloc((size_t)N * 4);
  float* ad2     = (float*)alloc((size_t)N * 4);
  float* we1     = (float*)alloc((size_t)(E + 64) * 4 * 4);
  float* wself1  = (float*)alloc((size_t)N * 4 * 4);
  float* we2     = (float*)alloc((size_t)(E + 64) * 4);
  float* wself2  = (float*)alloc((size_t)N * 4);
  float* den1    = (float*)alloc((size_t)N * 4 * 4);
  float* den2    = (float*)alloc((size_t)N * 4);
  float* S1      = (float*)alloc(256 * 4);
  float* T1      = (float*)alloc(256 * 4);
  float* S2      = (float*)alloc(64 * 4);
  float* T2      = (float*)alloc(64 * 4);
  ushort_t* W1t  = (ushort_t*)alloc((size_t)256 * 256 * 2);
  ushort_t* W2t  = (ushort_t*)alloc((size_t)64 * 256 * 2);
  ushort_t* h1b  = (ushort_t*)alloc((size_t)N * 256 * 2);
  ushort_t* h1a  = (ushort_t*)alloc((size_t)N * 256 * 2);
  ushort_t* h2b  = (ushort_t*)alloc((size_t)N * 64 * 2);

  float* out_reg = (float*)d_out;

  int prep_items = N + 256 * 256 + 256 * 64 + 256 + 64 + 64;
  prep_kernel<<<(prep_items + 255) / 256, 256, 0, stream>>>(
      counts, cursor, den1, den2, csr_src, W1, W2, W1t, W2t,
      b1, bn1w, bn1b, bn1m, bn1v, b2, bn2w, bn2b, bn2m, bn2v,
      S1, T1, S2, T2, N, E);

  hist_kernel<<<(E + 255) / 256, 256, 0, stream>>>(dstv, counts, E);
  scan_chunks_kernel<<<nb, 256, 0, stream>>>(counts, offsets, partials, N);
  scan_partials_kernel<<<1, 256, 0, stream>>>(partials, pprefix, nb);
  add_base_kernel<<<nb, 256, 0, stream>>>(offsets, pprefix, N, nb);
  scatter_kernel<<<(E + 255) / 256, 256, 0, stream>>>(srcv, dstv, offsets, cursor,
                                                      csr_src, csr_dst, E);

  const int nwb = (N + 3) / 4;
  const int ewb = (E + N + 255) / 256;

  // layer 1
  dim3 g1(4, (N + 127) / 128);
  mfma_gemm_fused<4, true><<<g1, 256, 0, stream>>>(x, W1t, h1b, a_src1, a_dst1, as1, ad1,
                                                   N, 256, 256, 4);
  edge_weights1<<<ewb, 256, 0, stream>>>(csr_src, csr_dst, as1, ad1, we1, wself1, den1, E, N);
  agg1_kernel<<<nwb, 256, 0, stream>>>(h1b, offsets, csr_src, we1, wself1, den1,
                                       S1, T1, h1a, N);

  // layer 2
  dim3 g2(1, (N + 63) / 64);
  mfma_gemm_fused<2, false><<<g2, 128, 0, stream>>>(h1a, W2t, h2b, a_src2, a_dst2, as2, ad2,
                                                    N, 64, 256, 1);
  edge_weights2<<<ewb, 256, 0, stream>>>(csr_src, csr_dst, as2, ad2, we2, wself2, den2, E, N);
  agg2_kernel<<<nwb, 256, 0, stream>>>(h2b, offsets, csr_src, we2, wself2, den2,
                                       S2, T2, Wr, br, Wc, bc, out_reg, out_reg + N, N);
}